// Round 4
// baseline (874.110 us; speedup 1.0000x reference)
//
#include <hip/hip_runtime.h>

#define F1 128
#define F2 64
// bucket = 512 consecutive nodes; requires N <= 256*512
#define BSH 9
#define BSZ 512

typedef unsigned long long u64;

// ---------------- CSR build (bucketed, LDS atomics) ----------------

__global__ __launch_bounds__(256) void k_bhist(const int* __restrict__ colv,
                                               int* __restrict__ bucket_cnt, int E) {
    __shared__ int l[256];
    int t = threadIdx.x;
    l[t] = 0;
    __syncthreads();
    for (int e = blockIdx.x * blockDim.x + t; e < E; e += gridDim.x * blockDim.x)
        atomicAdd(&l[colv[e] >> BSH], 1);
    __syncthreads();
    if (l[t]) atomicAdd(&bucket_cnt[t], l[t]);
}

__global__ __launch_bounds__(256) void k_bscan(const int* __restrict__ bucket_cnt,
                                               int* __restrict__ bucket_base,
                                               int* __restrict__ bucket_cur,
                                               int* __restrict__ rowptr_last,
                                               int NB, int E) {
    __shared__ int s[256];
    int t = threadIdx.x;
    int v = (t < NB) ? bucket_cnt[t] : 0;
    s[t] = v;
    __syncthreads();
    for (int d = 1; d < 256; d <<= 1) {
        int u = (t >= d) ? s[t - d] : 0;
        __syncthreads();
        s[t] += u;
        __syncthreads();
    }
    int excl = s[t] - v;
    if (t < NB) { bucket_base[t] = excl; bucket_cur[t] = excl; }
    if (t == NB - 1) bucket_base[NB] = s[t];
    if (t == 0) *rowptr_last = E;
}

// Each block stages 4096 edges in registers, reserves per-bucket runs with
// ONE global atomic per bucket, then writes packed (col<<32|row) bucket-major.
__global__ __launch_bounds__(256) void k_part(const int* __restrict__ rowv,
                                              const int* __restrict__ colv,
                                              int* __restrict__ bucket_cur,
                                              u64* __restrict__ ebuf, int E) {
    __shared__ int lcnt[256], lbase[256], loff[256];
    int t = threadIdx.x;
    lcnt[t] = 0; loff[t] = 0;
    __syncthreads();
    int rows[16], cols[16];
    int e0 = blockIdx.x * 4096;
#pragma unroll
    for (int it = 0; it < 16; it++) {
        int e = e0 + it * 256 + t;
        bool v = e < E;
        cols[it] = v ? colv[e] : -1;
        rows[it] = v ? rowv[e] : 0;
        if (v) atomicAdd(&lcnt[cols[it] >> BSH], 1);
    }
    __syncthreads();
    if (lcnt[t]) lbase[t] = atomicAdd(&bucket_cur[t], lcnt[t]);
    __syncthreads();
#pragma unroll
    for (int it = 0; it < 16; it++) {
        if (cols[it] >= 0) {
            int b = cols[it] >> BSH;
            int p = lbase[b] + atomicAdd(&loff[b], 1);
            ebuf[p] = ((u64)(unsigned)cols[it] << 32) | (unsigned)rows[it];
        }
    }
}

// One block per bucket: per-node counts + scan + placement all via LDS.
__global__ __launch_bounds__(512) void k_bfill(const u64* __restrict__ ebuf,
                                               const int* __restrict__ bucket_base,
                                               int* __restrict__ rowptr,
                                               float* __restrict__ dis,
                                               int* __restrict__ adj, int N) {
    __shared__ int cnt[BSZ], scn[BSZ], cur[BSZ];
    int t = threadIdx.x;
    int b = blockIdx.x;
    int e0 = bucket_base[b], e1 = bucket_base[b + 1];
    cnt[t] = 0;
    __syncthreads();
    for (int i = e0 + t; i < e1; i += BSZ) {
        int c = (int)(ebuf[i] >> 32);
        atomicAdd(&cnt[c & (BSZ - 1)], 1);
    }
    __syncthreads();
    scn[t] = cnt[t];
    __syncthreads();
    for (int d = 1; d < BSZ; d <<= 1) {
        int u = (t >= d) ? scn[t - d] : 0;
        __syncthreads();
        scn[t] += u;
        __syncthreads();
    }
    int excl = scn[t] - cnt[t];
    cur[t] = excl;
    int node = (b << BSH) + t;
    if (node < N) {
        rowptr[node] = e0 + excl;
        dis[node] = rsqrtf((float)(cnt[t] + 1));   // +1 self loop
    }
    __syncthreads();
    for (int i = e0 + t; i < e1; i += BSZ) {
        u64 p = ebuf[i];
        int c = (int)(p >> 32) & (BSZ - 1);
        int r = (int)(unsigned)p;
        int pos = atomicAdd(&cur[c], 1);
        adj[e0 + pos] = r;
    }
}

// ---------------- GEMM 1: g1 = dis[row] * (x @ W1) ----------------
// lane=row layout: wave owns a 64-row tile, acc[128]/lane. W1 in LDS read via
// wave-uniform ds_read_b128 broadcasts. Per k-chunk: 512 FMA per 1 global load
// -> self-latency-hiding even at 2 blocks/CU (64KB LDS).

__global__ __launch_bounds__(256, 2) void k_gemm1(const float* __restrict__ x,
                                                  const float* __restrict__ W,
                                                  const float* __restrict__ dis,
                                                  float* __restrict__ g, int N) {
    __shared__ float sW[F1 * F1];   // 64 KB
    {
        const float4* W4 = (const float4*)W;
        float4* s4 = (float4*)sW;
        for (int i = threadIdx.x; i < F1 * F1 / 4; i += 256) s4[i] = W4[i];
    }
    __syncthreads();
    int lane = threadIdx.x & 63;
    int wave = threadIdx.x >> 6;
    int ntiles = (N + 63) >> 6;
    for (int tile = blockIdx.x * 4 + wave; tile < ntiles; tile += gridDim.x * 4) {
        int row = (tile << 6) + lane;
        int r = min(row, N - 1);
        const float* xr = x + (size_t)r * F1;
        float acc[F1];
#pragma unroll
        for (int c = 0; c < F1; c++) acc[c] = 0.0f;
#pragma unroll 1
        for (int k = 0; k < F1; k += 4) {
            float4 xv = *(const float4*)(xr + k);
#pragma unroll
            for (int kk = 0; kk < 4; kk++) {
                float xs = ((const float*)&xv)[kk];
                const float4* wrow = (const float4*)&sW[(k + kk) * F1];
#pragma unroll
                for (int c4 = 0; c4 < F1 / 4; c4++) {
                    float4 wv = wrow[c4];   // wave-uniform broadcast
                    acc[c4 * 4 + 0] = fmaf(xs, wv.x, acc[c4 * 4 + 0]);
                    acc[c4 * 4 + 1] = fmaf(xs, wv.y, acc[c4 * 4 + 1]);
                    acc[c4 * 4 + 2] = fmaf(xs, wv.z, acc[c4 * 4 + 2]);
                    acc[c4 * 4 + 3] = fmaf(xs, wv.w, acc[c4 * 4 + 3]);
                }
            }
        }
        if (row < N) {
            float d = dis[row];
            float4* go = (float4*)(g + (size_t)row * F1);
#pragma unroll
            for (int c4 = 0; c4 < F1 / 4; c4++)
                go[c4] = make_float4(acc[c4 * 4 + 0] * d, acc[c4 * 4 + 1] * d,
                                     acc[c4 * 4 + 2] * d, acc[c4 * 4 + 3] * d);
        }
    }
}

// ---------------- Aggregation 1: z = relu(dis[i]*(g1[i] + sum g1[src]) + b1) ----------------

__global__ __launch_bounds__(256) void k_agg1(const float* __restrict__ g1,
                                              const int* __restrict__ rowptr,
                                              const int* __restrict__ adj,
                                              const float* __restrict__ dis,
                                              const float* __restrict__ b,
                                              float* __restrict__ z, int N) {
    int node = __builtin_amdgcn_readfirstlane(blockIdx.x * 4 + (threadIdx.x >> 6));
    if (node >= N) return;
    int lane = threadIdx.x & 63;
    const float2* gsrc = (const float2*)g1;   // row stride = 64 float2
    float2 acc = gsrc[(size_t)node * 64 + lane];   // self-loop term
    int s = rowptr[node], e = rowptr[node + 1];
    int j = s;
    for (; j + 3 < e; j += 4) {
        int s0 = adj[j], s1 = adj[j + 1], s2 = adj[j + 2], s3 = adj[j + 3];
        float2 v0 = gsrc[(size_t)s0 * 64 + lane];
        float2 v1 = gsrc[(size_t)s1 * 64 + lane];
        float2 v2 = gsrc[(size_t)s2 * 64 + lane];
        float2 v3 = gsrc[(size_t)s3 * 64 + lane];
        acc.x += (v0.x + v1.x) + (v2.x + v3.x);
        acc.y += (v0.y + v1.y) + (v2.y + v3.y);
    }
    for (; j < e; j++) {
        float2 v = gsrc[(size_t)adj[j] * 64 + lane];
        acc.x += v.x; acc.y += v.y;
    }
    float d = dis[node];
    float2 bb = ((const float2*)b)[lane];
    float2 o;
    o.x = fmaxf(fmaf(d, acc.x, bb.x), 0.0f);
    o.y = fmaxf(fmaf(d, acc.y, bb.y), 0.0f);
    ((float2*)z)[(size_t)node * 64 + lane] = o;
}

// ---------------- GEMM 2: g2 = dis[row] * (z @ W2) ----------------
// Same lane=row layout; acc[64]/lane; W2 32KB LDS -> 5 blocks/CU.

__global__ __launch_bounds__(256, 5) void k_gemm2(const float* __restrict__ z,
                                                  const float* __restrict__ W,
                                                  const float* __restrict__ dis,
                                                  float* __restrict__ g, int N) {
    __shared__ float sW[F1 * F2];   // 32 KB
    {
        const float4* W4 = (const float4*)W;
        float4* s4 = (float4*)sW;
        for (int i = threadIdx.x; i < F1 * F2 / 4; i += 256) s4[i] = W4[i];
    }
    __syncthreads();
    int lane = threadIdx.x & 63;
    int wave = threadIdx.x >> 6;
    int ntiles = (N + 63) >> 6;
    for (int tile = blockIdx.x * 4 + wave; tile < ntiles; tile += gridDim.x * 4) {
        int row = (tile << 6) + lane;
        int r = min(row, N - 1);
        const float* xr = z + (size_t)r * F1;
        float acc[F2];
#pragma unroll
        for (int c = 0; c < F2; c++) acc[c] = 0.0f;
#pragma unroll 1
        for (int k = 0; k < F1; k += 4) {
            float4 xv = *(const float4*)(xr + k);
#pragma unroll
            for (int kk = 0; kk < 4; kk++) {
                float xs = ((const float*)&xv)[kk];
                const float4* wrow = (const float4*)&sW[(k + kk) * F2];
#pragma unroll
                for (int c4 = 0; c4 < F2 / 4; c4++) {
                    float4 wv = wrow[c4];   // wave-uniform broadcast
                    acc[c4 * 4 + 0] = fmaf(xs, wv.x, acc[c4 * 4 + 0]);
                    acc[c4 * 4 + 1] = fmaf(xs, wv.y, acc[c4 * 4 + 1]);
                    acc[c4 * 4 + 2] = fmaf(xs, wv.z, acc[c4 * 4 + 2]);
                    acc[c4 * 4 + 3] = fmaf(xs, wv.w, acc[c4 * 4 + 3]);
                }
            }
        }
        if (row < N) {
            float d = dis[row];
            float4* go = (float4*)(g + (size_t)row * F2);
#pragma unroll
            for (int c4 = 0; c4 < F2 / 4; c4++)
                go[c4] = make_float4(acc[c4 * 4 + 0] * d, acc[c4 * 4 + 1] * d,
                                     acc[c4 * 4 + 2] * d, acc[c4 * 4 + 3] * d);
        }
    }
}

// ---------------- Aggregation 2: out = dis[i]*(g2[i] + sum g2[src]) + b2 ----------------

__global__ __launch_bounds__(256) void k_agg2(const float* __restrict__ g,
                                              const int* __restrict__ rowptr,
                                              const int* __restrict__ adj,
                                              const float* __restrict__ dis,
                                              const float* __restrict__ b,
                                              float* __restrict__ out, int N) {
    int node = __builtin_amdgcn_readfirstlane(blockIdx.x * 4 + (threadIdx.x >> 6));
    if (node >= N) return;
    int lane = threadIdx.x & 63;
    float acc = g[(size_t)node * F2 + lane];   // self-loop term
    int s = rowptr[node], e = rowptr[node + 1];
    int j = s;
    for (; j + 3 < e; j += 4) {
        int s0 = adj[j], s1 = adj[j + 1], s2 = adj[j + 2], s3 = adj[j + 3];
        float v0 = g[(size_t)s0 * F2 + lane];
        float v1 = g[(size_t)s1 * F2 + lane];
        float v2 = g[(size_t)s2 * F2 + lane];
        float v3 = g[(size_t)s3 * F2 + lane];
        acc += (v0 + v1) + (v2 + v3);
    }
    for (; j < e; j++) acc += g[(size_t)adj[j] * F2 + lane];
    out[(size_t)node * F2 + lane] = fmaf(dis[node], acc, b[lane]);
}

// ---------------- launch ----------------

extern "C" void kernel_launch(void* const* d_in, const int* in_sizes, int n_in,
                              void* d_out, int out_size, void* d_ws, size_t ws_size,
                              hipStream_t stream) {
    const float* x  = (const float*)d_in[0];
    const int*   ei = (const int*)d_in[1];
    const float* W1 = (const float*)d_in[2];
    const float* b1 = (const float*)d_in[3];
    const float* W2 = (const float*)d_in[4];
    const float* b2 = (const float*)d_in[5];
    float* out = (float*)d_out;

    const int N = in_sizes[0] / F1;
    const int E = in_sizes[1] / 2;
    const int NB = (N + BSZ - 1) >> BSH;   // 196 for N=100000; must be <= 256
    const int* rowv = ei;        // sources
    const int* colv = ei + E;    // targets

    char* ws = (char*)d_ws;
    size_t off = 0;
    auto take = [&](size_t bytes) -> void* {
        void* p = ws + off;
        off += (bytes + 255) & ~(size_t)255;
        return p;
    };
    float* g1      = (float*)take((size_t)N * F1 * 4);   // 51.2 MB
    float* z       = (float*)take((size_t)N * F1 * 4);   // 51.2 MB
    float* g2      = g1;                 // g1 dead after agg1 -> reuse
    u64*   ebuf    = (u64*)g1;           // ebuf (12.8 MB) dead before gemm1 writes g1
    float* dis     = (float*)take((size_t)N * 4);
    int*   rowptr  = (int*)take((size_t)(N + 1) * 4);
    int*   adj     = (int*)take((size_t)E * 4);          // 6.4 MB
    int*   bucket_cnt  = (int*)take(256 * 4);
    int*   bucket_base = (int*)take(257 * 4);
    int*   bucket_cur  = (int*)take(256 * 4);

    hipMemsetAsync(bucket_cnt, 0, 256 * 4, stream);

    k_bhist<<<256, 256, 0, stream>>>(colv, bucket_cnt, E);
    k_bscan<<<1, 256, 0, stream>>>(bucket_cnt, bucket_base, bucket_cur, rowptr + N, NB, E);
    k_part<<<(E + 4095) / 4096, 256, 0, stream>>>(rowv, colv, bucket_cur, ebuf, E);
    k_bfill<<<NB, BSZ, 0, stream>>>(ebuf, bucket_base, rowptr, dis, adj, N);

    k_gemm1<<<512, 256, 0, stream>>>(x, W1, dis, g1, N);
    k_agg1<<<(N + 3) / 4, 256, 0, stream>>>(g1, rowptr, adj, dis, b1, z, N);
    k_gemm2<<<512, 256, 0, stream>>>(z, W2, dis, g2, N);
    k_agg2<<<(N + 3) / 4, 256, 0, stream>>>(g2, rowptr, adj, dis, b2, out, N);
}

// Round 5
// 426.207 us; speedup vs baseline: 2.0509x; 2.0509x over previous
//
#include <hip/hip_runtime.h>

#define F1 128
#define F2 64
// bucket = 512 consecutive nodes; requires N <= 256*512
#define BSH 9
#define BSZ 512

typedef unsigned long long u64;

// ---------------- CSR build (bucketed, LDS atomics) ----------------

__global__ __launch_bounds__(256) void k_bhist(const int* __restrict__ colv,
                                               int* __restrict__ bucket_cnt, int E) {
    __shared__ int l[256];
    int t = threadIdx.x;
    l[t] = 0;
    __syncthreads();
    for (int e = blockIdx.x * blockDim.x + t; e < E; e += gridDim.x * blockDim.x)
        atomicAdd(&l[colv[e] >> BSH], 1);
    __syncthreads();
    if (l[t]) atomicAdd(&bucket_cnt[t], l[t]);
}

__global__ __launch_bounds__(256) void k_bscan(const int* __restrict__ bucket_cnt,
                                               int* __restrict__ bucket_base,
                                               int* __restrict__ bucket_cur,
                                               int* __restrict__ rowptr_last,
                                               int NB, int E) {
    __shared__ int s[256];
    int t = threadIdx.x;
    int v = (t < NB) ? bucket_cnt[t] : 0;
    s[t] = v;
    __syncthreads();
    for (int d = 1; d < 256; d <<= 1) {
        int u = (t >= d) ? s[t - d] : 0;
        __syncthreads();
        s[t] += u;
        __syncthreads();
    }
    int excl = s[t] - v;
    if (t < NB) { bucket_base[t] = excl; bucket_cur[t] = excl; }
    if (t == NB - 1) bucket_base[NB] = s[t];
    if (t == 0) *rowptr_last = E;
}

// Each block stages 4096 edges in registers, reserves per-bucket runs with
// ONE global atomic per bucket, then writes packed (col<<32|row) bucket-major.
__global__ __launch_bounds__(256) void k_part(const int* __restrict__ rowv,
                                              const int* __restrict__ colv,
                                              int* __restrict__ bucket_cur,
                                              u64* __restrict__ ebuf, int E) {
    __shared__ int lcnt[256], lbase[256], loff[256];
    int t = threadIdx.x;
    lcnt[t] = 0; loff[t] = 0;
    __syncthreads();
    int rows[16], cols[16];
    int e0 = blockIdx.x * 4096;
#pragma unroll
    for (int it = 0; it < 16; it++) {
        int e = e0 + it * 256 + t;
        bool v = e < E;
        cols[it] = v ? colv[e] : -1;
        rows[it] = v ? rowv[e] : 0;
        if (v) atomicAdd(&lcnt[cols[it] >> BSH], 1);
    }
    __syncthreads();
    if (lcnt[t]) lbase[t] = atomicAdd(&bucket_cur[t], lcnt[t]);
    __syncthreads();
#pragma unroll
    for (int it = 0; it < 16; it++) {
        if (cols[it] >= 0) {
            int b = cols[it] >> BSH;
            int p = lbase[b] + atomicAdd(&loff[b], 1);
            ebuf[p] = ((u64)(unsigned)cols[it] << 32) | (unsigned)rows[it];
        }
    }
}

// One block per bucket: per-node counts + scan + placement all via LDS.
__global__ __launch_bounds__(512) void k_bfill(const u64* __restrict__ ebuf,
                                               const int* __restrict__ bucket_base,
                                               int* __restrict__ rowptr,
                                               float* __restrict__ dis,
                                               int* __restrict__ adj, int N) {
    __shared__ int cnt[BSZ], scn[BSZ], cur[BSZ];
    int t = threadIdx.x;
    int b = blockIdx.x;
    int e0 = bucket_base[b], e1 = bucket_base[b + 1];
    cnt[t] = 0;
    __syncthreads();
    for (int i = e0 + t; i < e1; i += BSZ) {
        int c = (int)(ebuf[i] >> 32);
        atomicAdd(&cnt[c & (BSZ - 1)], 1);
    }
    __syncthreads();
    scn[t] = cnt[t];
    __syncthreads();
    for (int d = 1; d < BSZ; d <<= 1) {
        int u = (t >= d) ? scn[t - d] : 0;
        __syncthreads();
        scn[t] += u;
        __syncthreads();
    }
    int excl = scn[t] - cnt[t];
    cur[t] = excl;
    int node = (b << BSH) + t;
    if (node < N) {
        rowptr[node] = e0 + excl;
        dis[node] = rsqrtf((float)(cnt[t] + 1));   // +1 self loop
    }
    __syncthreads();
    for (int i = e0 + t; i < e1; i += BSZ) {
        u64 p = ebuf[i];
        int c = (int)(p >> 32) & (BSZ - 1);
        int r = (int)(unsigned)p;
        int pos = atomicAdd(&cur[c], 1);
        adj[e0 + pos] = r;
    }
}

// ---------------- GEMM 1: g1 = dis[row] * (x @ W1) ----------------
// Block = 128-row tile, 4 waves. Wave w computes cols [32w,32w+32); lane owns
// rows (row0, row0+64) -> acc[2][32] = 64 VGPRs, no spill at 128-VGPR cap.
// x: per-lane global b128 of own row (L1-served across waves).
// W: wave-uniform address (readfirstlane c0) -> scalar s_load, SGPR FMA operand.

__global__ __launch_bounds__(256, 4) void k_gemm1(const float* __restrict__ x,
                                                  const float* __restrict__ W,
                                                  const float* __restrict__ dis,
                                                  float* __restrict__ g, int N) {
    int lane = threadIdx.x & 63;
    int c0 = __builtin_amdgcn_readfirstlane((threadIdx.x >> 6) << 5);   // 0,32,64,96
    int row0 = (blockIdx.x << 7) + lane;          // rows row0 and row0+64
    int ra = min(row0, N - 1);
    int rb = min(row0 + 64, N - 1);
    const float4* xa = (const float4*)(x + (size_t)ra * F1);
    const float4* xb = (const float4*)(x + (size_t)rb * F1);
    float acc0[32], acc1[32];
#pragma unroll
    for (int c = 0; c < 32; c++) { acc0[c] = 0.0f; acc1[c] = 0.0f; }
#pragma unroll 2
    for (int k4 = 0; k4 < F1 / 4; k4++) {
        float4 va = xa[k4];
        float4 vb = xb[k4];
#pragma unroll
        for (int kk = 0; kk < 4; kk++) {
            const float4* wr = (const float4*)(W + (size_t)(k4 * 4 + kk) * F1 + c0);
            float sa = ((const float*)&va)[kk];
            float sb = ((const float*)&vb)[kk];
#pragma unroll
            for (int c4 = 0; c4 < 8; c4++) {
                float4 wv = wr[c4];   // wave-uniform -> s_load
                acc0[c4 * 4 + 0] = fmaf(sa, wv.x, acc0[c4 * 4 + 0]);
                acc0[c4 * 4 + 1] = fmaf(sa, wv.y, acc0[c4 * 4 + 1]);
                acc0[c4 * 4 + 2] = fmaf(sa, wv.z, acc0[c4 * 4 + 2]);
                acc0[c4 * 4 + 3] = fmaf(sa, wv.w, acc0[c4 * 4 + 3]);
                acc1[c4 * 4 + 0] = fmaf(sb, wv.x, acc1[c4 * 4 + 0]);
                acc1[c4 * 4 + 1] = fmaf(sb, wv.y, acc1[c4 * 4 + 1]);
                acc1[c4 * 4 + 2] = fmaf(sb, wv.z, acc1[c4 * 4 + 2]);
                acc1[c4 * 4 + 3] = fmaf(sb, wv.w, acc1[c4 * 4 + 3]);
            }
        }
    }
    if (row0 < N) {
        float d = dis[row0];
        float4* go = (float4*)(g + (size_t)row0 * F1 + c0);
#pragma unroll
        for (int c4 = 0; c4 < 8; c4++)
            go[c4] = make_float4(acc0[c4 * 4 + 0] * d, acc0[c4 * 4 + 1] * d,
                                 acc0[c4 * 4 + 2] * d, acc0[c4 * 4 + 3] * d);
    }
    if (row0 + 64 < N) {
        float d = dis[row0 + 64];
        float4* go = (float4*)(g + (size_t)(row0 + 64) * F1 + c0);
#pragma unroll
        for (int c4 = 0; c4 < 8; c4++)
            go[c4] = make_float4(acc1[c4 * 4 + 0] * d, acc1[c4 * 4 + 1] * d,
                                 acc1[c4 * 4 + 2] * d, acc1[c4 * 4 + 3] * d);
    }
}

// ---------------- Aggregation 1: z = relu(dis[i]*(g1[i] + sum g1[src]) + b1) ----------------

__global__ __launch_bounds__(256) void k_agg1(const float* __restrict__ g1,
                                              const int* __restrict__ rowptr,
                                              const int* __restrict__ adj,
                                              const float* __restrict__ dis,
                                              const float* __restrict__ b,
                                              float* __restrict__ z, int N) {
    int node = __builtin_amdgcn_readfirstlane(blockIdx.x * 4 + (threadIdx.x >> 6));
    if (node >= N) return;
    int lane = threadIdx.x & 63;
    const float2* gsrc = (const float2*)g1;   // row stride = 64 float2
    float2 acc = gsrc[(size_t)node * 64 + lane];   // self-loop term
    int s = rowptr[node], e = rowptr[node + 1];
    int j = s;
    for (; j + 3 < e; j += 4) {
        int s0 = adj[j], s1 = adj[j + 1], s2 = adj[j + 2], s3 = adj[j + 3];
        float2 v0 = gsrc[(size_t)s0 * 64 + lane];
        float2 v1 = gsrc[(size_t)s1 * 64 + lane];
        float2 v2 = gsrc[(size_t)s2 * 64 + lane];
        float2 v3 = gsrc[(size_t)s3 * 64 + lane];
        acc.x += (v0.x + v1.x) + (v2.x + v3.x);
        acc.y += (v0.y + v1.y) + (v2.y + v3.y);
    }
    for (; j < e; j++) {
        float2 v = gsrc[(size_t)adj[j] * 64 + lane];
        acc.x += v.x; acc.y += v.y;
    }
    float d = dis[node];
    float2 bb = ((const float2*)b)[lane];
    float2 o;
    o.x = fmaxf(fmaf(d, acc.x, bb.x), 0.0f);
    o.y = fmaxf(fmaf(d, acc.y, bb.y), 0.0f);
    ((float2*)z)[(size_t)node * 64 + lane] = o;
}

// ---------------- GEMM 2: g2 = dis[row] * (z @ W2) ----------------
// Same structure; wave w computes cols [16w,16w+16); acc[2][16] = 32 VGPRs.

__global__ __launch_bounds__(256, 4) void k_gemm2(const float* __restrict__ z,
                                                  const float* __restrict__ W,
                                                  const float* __restrict__ dis,
                                                  float* __restrict__ g, int N) {
    int lane = threadIdx.x & 63;
    int c0 = __builtin_amdgcn_readfirstlane((threadIdx.x >> 6) << 4);   // 0,16,32,48
    int row0 = (blockIdx.x << 7) + lane;
    int ra = min(row0, N - 1);
    int rb = min(row0 + 64, N - 1);
    const float4* xa = (const float4*)(z + (size_t)ra * F1);
    const float4* xb = (const float4*)(z + (size_t)rb * F1);
    float acc0[16], acc1[16];
#pragma unroll
    for (int c = 0; c < 16; c++) { acc0[c] = 0.0f; acc1[c] = 0.0f; }
#pragma unroll 2
    for (int k4 = 0; k4 < F1 / 4; k4++) {
        float4 va = xa[k4];
        float4 vb = xb[k4];
#pragma unroll
        for (int kk = 0; kk < 4; kk++) {
            const float4* wr = (const float4*)(W + (size_t)(k4 * 4 + kk) * F2 + c0);
            float sa = ((const float*)&va)[kk];
            float sb = ((const float*)&vb)[kk];
#pragma unroll
            for (int c4 = 0; c4 < 4; c4++) {
                float4 wv = wr[c4];   // wave-uniform -> s_load
                acc0[c4 * 4 + 0] = fmaf(sa, wv.x, acc0[c4 * 4 + 0]);
                acc0[c4 * 4 + 1] = fmaf(sa, wv.y, acc0[c4 * 4 + 1]);
                acc0[c4 * 4 + 2] = fmaf(sa, wv.z, acc0[c4 * 4 + 2]);
                acc0[c4 * 4 + 3] = fmaf(sa, wv.w, acc0[c4 * 4 + 3]);
                acc1[c4 * 4 + 0] = fmaf(sb, wv.x, acc1[c4 * 4 + 0]);
                acc1[c4 * 4 + 1] = fmaf(sb, wv.y, acc1[c4 * 4 + 1]);
                acc1[c4 * 4 + 2] = fmaf(sb, wv.z, acc1[c4 * 4 + 2]);
                acc1[c4 * 4 + 3] = fmaf(sb, wv.w, acc1[c4 * 4 + 3]);
            }
        }
    }
    if (row0 < N) {
        float d = dis[row0];
        float4* go = (float4*)(g + (size_t)row0 * F2 + c0);
#pragma unroll
        for (int c4 = 0; c4 < 4; c4++)
            go[c4] = make_float4(acc0[c4 * 4 + 0] * d, acc0[c4 * 4 + 1] * d,
                                 acc0[c4 * 4 + 2] * d, acc0[c4 * 4 + 3] * d);
    }
    if (row0 + 64 < N) {
        float d = dis[row0 + 64];
        float4* go = (float4*)(g + (size_t)(row0 + 64) * F2 + c0);
#pragma unroll
        for (int c4 = 0; c4 < 4; c4++)
            go[c4] = make_float4(acc1[c4 * 4 + 0] * d, acc1[c4 * 4 + 1] * d,
                                 acc1[c4 * 4 + 2] * d, acc1[c4 * 4 + 3] * d);
    }
}

// ---------------- Aggregation 2: out = dis[i]*(g2[i] + sum g2[src]) + b2 ----------------

__global__ __launch_bounds__(256) void k_agg2(const float* __restrict__ g,
                                              const int* __restrict__ rowptr,
                                              const int* __restrict__ adj,
                                              const float* __restrict__ dis,
                                              const float* __restrict__ b,
                                              float* __restrict__ out, int N) {
    int node = __builtin_amdgcn_readfirstlane(blockIdx.x * 4 + (threadIdx.x >> 6));
    if (node >= N) return;
    int lane = threadIdx.x & 63;
    float acc = g[(size_t)node * F2 + lane];   // self-loop term
    int s = rowptr[node], e = rowptr[node + 1];
    int j = s;
    for (; j + 3 < e; j += 4) {
        int s0 = adj[j], s1 = adj[j + 1], s2 = adj[j + 2], s3 = adj[j + 3];
        float v0 = g[(size_t)s0 * F2 + lane];
        float v1 = g[(size_t)s1 * F2 + lane];
        float v2 = g[(size_t)s2 * F2 + lane];
        float v3 = g[(size_t)s3 * F2 + lane];
        acc += (v0 + v1) + (v2 + v3);
    }
    for (; j < e; j++) acc += g[(size_t)adj[j] * F2 + lane];
    out[(size_t)node * F2 + lane] = fmaf(dis[node], acc, b[lane]);
}

// ---------------- launch ----------------

extern "C" void kernel_launch(void* const* d_in, const int* in_sizes, int n_in,
                              void* d_out, int out_size, void* d_ws, size_t ws_size,
                              hipStream_t stream) {
    const float* x  = (const float*)d_in[0];
    const int*   ei = (const int*)d_in[1];
    const float* W1 = (const float*)d_in[2];
    const float* b1 = (const float*)d_in[3];
    const float* W2 = (const float*)d_in[4];
    const float* b2 = (const float*)d_in[5];
    float* out = (float*)d_out;

    const int N = in_sizes[0] / F1;
    const int E = in_sizes[1] / 2;
    const int NB = (N + BSZ - 1) >> BSH;   // 196 for N=100000; must be <= 256
    const int* rowv = ei;        // sources
    const int* colv = ei + E;    // targets

    char* ws = (char*)d_ws;
    size_t off = 0;
    auto take = [&](size_t bytes) -> void* {
        void* p = ws + off;
        off += (bytes + 255) & ~(size_t)255;
        return p;
    };
    float* g1      = (float*)take((size_t)N * F1 * 4);   // 51.2 MB
    float* z       = (float*)take((size_t)N * F1 * 4);   // 51.2 MB
    float* g2      = g1;                 // g1 dead after agg1 -> reuse
    u64*   ebuf    = (u64*)g1;           // ebuf (12.8 MB) dead before gemm1 writes g1
    float* dis     = (float*)take((size_t)N * 4);
    int*   rowptr  = (int*)take((size_t)(N + 1) * 4);
    int*   adj     = (int*)take((size_t)E * 4);          // 6.4 MB
    int*   bucket_cnt  = (int*)take(256 * 4);
    int*   bucket_base = (int*)take(257 * 4);
    int*   bucket_cur  = (int*)take(256 * 4);

    hipMemsetAsync(bucket_cnt, 0, 256 * 4, stream);

    k_bhist<<<256, 256, 0, stream>>>(colv, bucket_cnt, E);
    k_bscan<<<1, 256, 0, stream>>>(bucket_cnt, bucket_base, bucket_cur, rowptr + N, NB, E);
    k_part<<<(E + 4095) / 4096, 256, 0, stream>>>(rowv, colv, bucket_cur, ebuf, E);
    k_bfill<<<NB, BSZ, 0, stream>>>(ebuf, bucket_base, rowptr, dis, adj, N);

    int tiles = (N + 127) >> 7;
    k_gemm1<<<tiles, 256, 0, stream>>>(x, W1, dis, g1, N);
    k_agg1<<<(N + 3) / 4, 256, 0, stream>>>(g1, rowptr, adj, dis, b1, z, N);
    k_gemm2<<<tiles, 256, 0, stream>>>(z, W2, dis, g2, N);
    k_agg2<<<(N + 3) / 4, 256, 0, stream>>>(g2, rowptr, adj, dis, b2, out, N);
}

// Round 6
// 352.455 us; speedup vs baseline: 2.4801x; 1.2093x over previous
//
#include <hip/hip_runtime.h>

#define F1 128
#define F2 64
// bucket = 512 consecutive nodes; requires N <= 256*512 and N < 2^17 (u32 ebuf pack)
#define BSH 9
#define BSZ 512

typedef unsigned int u32;
typedef unsigned short u16;

// bf16 helpers (manual, header-version-proof). RNE pack, shift unpack.
__device__ __forceinline__ u32 bf16rne(float f) {
    u32 u = __float_as_uint(f);
    return (u + 0x7FFFu + ((u >> 16) & 1u)) >> 16;
}
__device__ __forceinline__ u32 pack2(float lo, float hi) {
    return bf16rne(lo) | (bf16rne(hi) << 16);
}
__device__ __forceinline__ float bflo(u32 u) { return __uint_as_float(u << 16); }
__device__ __forceinline__ float bfhi(u32 u) { return __uint_as_float(u & 0xFFFF0000u); }
__device__ __forceinline__ float bf1(u16 u) { return __uint_as_float((u32)u << 16); }

// ---------------- CSR build (bucketed, LDS atomics) ----------------

__global__ __launch_bounds__(256) void k_bhist(const int* __restrict__ colv,
                                               int* __restrict__ bucket_cnt, int E) {
    __shared__ int l[256];
    int t = threadIdx.x;
    l[t] = 0;
    __syncthreads();
    for (int e = blockIdx.x * blockDim.x + t; e < E; e += gridDim.x * blockDim.x)
        atomicAdd(&l[colv[e] >> BSH], 1);
    __syncthreads();
    if (l[t]) atomicAdd(&bucket_cnt[t], l[t]);
}

__global__ __launch_bounds__(256) void k_bscan(const int* __restrict__ bucket_cnt,
                                               int* __restrict__ bucket_base,
                                               int* __restrict__ bucket_cur,
                                               int* __restrict__ rowptr_last,
                                               int NB, int E) {
    __shared__ int s[256];
    int t = threadIdx.x;
    int v = (t < NB) ? bucket_cnt[t] : 0;
    s[t] = v;
    __syncthreads();
    for (int d = 1; d < 256; d <<= 1) {
        int u = (t >= d) ? s[t - d] : 0;
        __syncthreads();
        s[t] += u;
        __syncthreads();
    }
    int excl = s[t] - v;
    if (t < NB) { bucket_base[t] = excl; bucket_cur[t] = excl; }
    if (t == NB - 1) bucket_base[NB] = s[t];
    if (t == 0) *rowptr_last = E;
}

// Stage 4096 edges in registers, reserve per-bucket runs with ONE global atomic
// per bucket, write packed (c_local<<17 | row) u32 bucket-major.
__global__ __launch_bounds__(256) void k_part(const int* __restrict__ rowv,
                                              const int* __restrict__ colv,
                                              int* __restrict__ bucket_cur,
                                              u32* __restrict__ ebuf, int E) {
    __shared__ int lcnt[256], lbase[256], loff[256];
    int t = threadIdx.x;
    lcnt[t] = 0; loff[t] = 0;
    __syncthreads();
    int rows[16], cols[16];
    int e0 = blockIdx.x * 4096;
#pragma unroll
    for (int it = 0; it < 16; it++) {
        int e = e0 + it * 256 + t;
        bool v = e < E;
        cols[it] = v ? colv[e] : -1;
        rows[it] = v ? rowv[e] : 0;
        if (v) atomicAdd(&lcnt[cols[it] >> BSH], 1);
    }
    __syncthreads();
    if (lcnt[t]) lbase[t] = atomicAdd(&bucket_cur[t], lcnt[t]);
    __syncthreads();
#pragma unroll
    for (int it = 0; it < 16; it++) {
        if (cols[it] >= 0) {
            int b = cols[it] >> BSH;
            int p = lbase[b] + atomicAdd(&loff[b], 1);
            ebuf[p] = ((u32)(cols[it] & (BSZ - 1)) << 17) | (u32)rows[it];
        }
    }
}

// One block per bucket: per-node counts + scan + placement all via LDS.
__global__ __launch_bounds__(512) void k_bfill(const u32* __restrict__ ebuf,
                                               const int* __restrict__ bucket_base,
                                               int* __restrict__ rowptr,
                                               float* __restrict__ dis,
                                               int* __restrict__ adj, int N) {
    __shared__ int cnt[BSZ], scn[BSZ], cur[BSZ];
    int t = threadIdx.x;
    int b = blockIdx.x;
    int e0 = bucket_base[b], e1 = bucket_base[b + 1];
    cnt[t] = 0;
    __syncthreads();
    for (int i = e0 + t; i < e1; i += BSZ)
        atomicAdd(&cnt[ebuf[i] >> 17], 1);
    __syncthreads();
    scn[t] = cnt[t];
    __syncthreads();
    for (int d = 1; d < BSZ; d <<= 1) {
        int u = (t >= d) ? scn[t - d] : 0;
        __syncthreads();
        scn[t] += u;
        __syncthreads();
    }
    int excl = scn[t] - cnt[t];
    cur[t] = excl;
    int node = (b << BSH) + t;
    if (node < N) {
        rowptr[node] = e0 + excl;
        dis[node] = rsqrtf((float)(cnt[t] + 1));   // +1 self loop
    }
    __syncthreads();
    for (int i = e0 + t; i < e1; i += BSZ) {
        u32 p = ebuf[i];
        int c = p >> 17;
        int r = (int)(p & 0x1FFFFu);
        int pos = atomicAdd(&cur[c], 1);
        adj[e0 + pos] = r;
    }
}

// ---------------- GEMM 1: g1(bf16) = dis[row] * (x @ W1) ----------------
// Block = 128-row tile, 4 waves. Wave w computes cols [32w,32w+32); lane owns
// rows (row0, row0+64) -> acc[2][32] = 64 VGPRs. W via wave-uniform s_load.

__global__ __launch_bounds__(256, 4) void k_gemm1(const float* __restrict__ x,
                                                  const float* __restrict__ W,
                                                  const float* __restrict__ dis,
                                                  u16* __restrict__ gb, int N) {
    int lane = threadIdx.x & 63;
    int c0 = __builtin_amdgcn_readfirstlane((threadIdx.x >> 6) << 5);   // 0,32,64,96
    int row0 = (blockIdx.x << 7) + lane;          // rows row0 and row0+64
    int ra = min(row0, N - 1);
    int rb = min(row0 + 64, N - 1);
    const float4* xa = (const float4*)(x + (size_t)ra * F1);
    const float4* xb = (const float4*)(x + (size_t)rb * F1);
    float acc0[32], acc1[32];
#pragma unroll
    for (int c = 0; c < 32; c++) { acc0[c] = 0.0f; acc1[c] = 0.0f; }
#pragma unroll 2
    for (int k4 = 0; k4 < F1 / 4; k4++) {
        float4 va = xa[k4];
        float4 vb = xb[k4];
#pragma unroll
        for (int kk = 0; kk < 4; kk++) {
            const float4* wr = (const float4*)(W + (size_t)(k4 * 4 + kk) * F1 + c0);
            float sa = ((const float*)&va)[kk];
            float sb = ((const float*)&vb)[kk];
#pragma unroll
            for (int c4 = 0; c4 < 8; c4++) {
                float4 wv = wr[c4];   // wave-uniform -> s_load
                acc0[c4 * 4 + 0] = fmaf(sa, wv.x, acc0[c4 * 4 + 0]);
                acc0[c4 * 4 + 1] = fmaf(sa, wv.y, acc0[c4 * 4 + 1]);
                acc0[c4 * 4 + 2] = fmaf(sa, wv.z, acc0[c4 * 4 + 2]);
                acc0[c4 * 4 + 3] = fmaf(sa, wv.w, acc0[c4 * 4 + 3]);
                acc1[c4 * 4 + 0] = fmaf(sb, wv.x, acc1[c4 * 4 + 0]);
                acc1[c4 * 4 + 1] = fmaf(sb, wv.y, acc1[c4 * 4 + 1]);
                acc1[c4 * 4 + 2] = fmaf(sb, wv.z, acc1[c4 * 4 + 2]);
                acc1[c4 * 4 + 3] = fmaf(sb, wv.w, acc1[c4 * 4 + 3]);
            }
        }
    }
    if (row0 < N) {
        float d = dis[row0];
        uint4* gp = (uint4*)(gb + (size_t)row0 * F1 + c0);
#pragma unroll
        for (int c8 = 0; c8 < 4; c8++) {
            uint4 o;
            o.x = pack2(acc0[c8 * 8 + 0] * d, acc0[c8 * 8 + 1] * d);
            o.y = pack2(acc0[c8 * 8 + 2] * d, acc0[c8 * 8 + 3] * d);
            o.z = pack2(acc0[c8 * 8 + 4] * d, acc0[c8 * 8 + 5] * d);
            o.w = pack2(acc0[c8 * 8 + 6] * d, acc0[c8 * 8 + 7] * d);
            gp[c8] = o;
        }
    }
    if (row0 + 64 < N) {
        float d = dis[row0 + 64];
        uint4* gp = (uint4*)(gb + (size_t)(row0 + 64) * F1 + c0);
#pragma unroll
        for (int c8 = 0; c8 < 4; c8++) {
            uint4 o;
            o.x = pack2(acc1[c8 * 8 + 0] * d, acc1[c8 * 8 + 1] * d);
            o.y = pack2(acc1[c8 * 8 + 2] * d, acc1[c8 * 8 + 3] * d);
            o.z = pack2(acc1[c8 * 8 + 4] * d, acc1[c8 * 8 + 5] * d);
            o.w = pack2(acc1[c8 * 8 + 6] * d, acc1[c8 * 8 + 7] * d);
            gp[c8] = o;
        }
    }
}

// ---------------- Aggregation 1: z(bf16) = relu(dis[i]*(g1[i] + sum g1[src]) + b1) ----------------
// Row = 64 uints (128 bf16); lane owns cols 2*lane, 2*lane+1.

__global__ __launch_bounds__(256) void k_agg1(const u32* __restrict__ g1,
                                              const int* __restrict__ rowptr,
                                              const int* __restrict__ adj,
                                              const float* __restrict__ dis,
                                              const float* __restrict__ b,
                                              u32* __restrict__ z, int N) {
    int node = __builtin_amdgcn_readfirstlane(blockIdx.x * 4 + (threadIdx.x >> 6));
    if (node >= N) return;
    int lane = threadIdx.x & 63;
    u32 sv = g1[(size_t)node * 64 + lane];   // self-loop term
    float ax = bflo(sv), ay = bfhi(sv);
    int s = rowptr[node], e = rowptr[node + 1];
    int j = s;
    for (; j + 3 < e; j += 4) {
        int s0 = adj[j], s1 = adj[j + 1], s2 = adj[j + 2], s3 = adj[j + 3];
        u32 v0 = g1[(size_t)s0 * 64 + lane];
        u32 v1 = g1[(size_t)s1 * 64 + lane];
        u32 v2 = g1[(size_t)s2 * 64 + lane];
        u32 v3 = g1[(size_t)s3 * 64 + lane];
        ax += (bflo(v0) + bflo(v1)) + (bflo(v2) + bflo(v3));
        ay += (bfhi(v0) + bfhi(v1)) + (bfhi(v2) + bfhi(v3));
    }
    for (; j < e; j++) {
        u32 v = g1[(size_t)adj[j] * 64 + lane];
        ax += bflo(v); ay += bfhi(v);
    }
    float d = dis[node];
    float2 bb = ((const float2*)b)[lane];
    float ox = fmaxf(fmaf(d, ax, bb.x), 0.0f);
    float oy = fmaxf(fmaf(d, ay, bb.y), 0.0f);
    z[(size_t)node * 64 + lane] = pack2(ox, oy);
}

// ---------------- GEMM 2: g2(bf16) = dis[row] * (z @ W2) ----------------
// Wave w computes cols [16w,16w+16); lane owns rows (row0, row0+64).
// z rows read as packed bf16 (uint4 = 8 k-values).

__global__ __launch_bounds__(256, 4) void k_gemm2(const u32* __restrict__ z,
                                                  const float* __restrict__ W,
                                                  const float* __restrict__ dis,
                                                  u16* __restrict__ gb, int N) {
    int lane = threadIdx.x & 63;
    int c0 = __builtin_amdgcn_readfirstlane((threadIdx.x >> 6) << 4);   // 0,16,32,48
    int row0 = (blockIdx.x << 7) + lane;
    int ra = min(row0, N - 1);
    int rb = min(row0 + 64, N - 1);
    const uint4* za = (const uint4*)(z + (size_t)ra * 64);
    const uint4* zb = (const uint4*)(z + (size_t)rb * 64);
    float acc0[16], acc1[16];
#pragma unroll
    for (int c = 0; c < 16; c++) { acc0[c] = 0.0f; acc1[c] = 0.0f; }
#pragma unroll 2
    for (int k8 = 0; k8 < F1 / 8; k8++) {
        uint4 ua = za[k8];
        uint4 ub = zb[k8];
        float fa[8], fb[8];
        fa[0] = bflo(ua.x); fa[1] = bfhi(ua.x); fa[2] = bflo(ua.y); fa[3] = bfhi(ua.y);
        fa[4] = bflo(ua.z); fa[5] = bfhi(ua.z); fa[6] = bflo(ua.w); fa[7] = bfhi(ua.w);
        fb[0] = bflo(ub.x); fb[1] = bfhi(ub.x); fb[2] = bflo(ub.y); fb[3] = bfhi(ub.y);
        fb[4] = bflo(ub.z); fb[5] = bfhi(ub.z); fb[6] = bflo(ub.w); fb[7] = bfhi(ub.w);
#pragma unroll
        for (int kk = 0; kk < 8; kk++) {
            const float4* wr = (const float4*)(W + (size_t)(k8 * 8 + kk) * F2 + c0);
#pragma unroll
            for (int c4 = 0; c4 < 4; c4++) {
                float4 wv = wr[c4];   // wave-uniform -> s_load
                acc0[c4 * 4 + 0] = fmaf(fa[kk], wv.x, acc0[c4 * 4 + 0]);
                acc0[c4 * 4 + 1] = fmaf(fa[kk], wv.y, acc0[c4 * 4 + 1]);
                acc0[c4 * 4 + 2] = fmaf(fa[kk], wv.z, acc0[c4 * 4 + 2]);
                acc0[c4 * 4 + 3] = fmaf(fa[kk], wv.w, acc0[c4 * 4 + 3]);
                acc1[c4 * 4 + 0] = fmaf(fb[kk], wv.x, acc1[c4 * 4 + 0]);
                acc1[c4 * 4 + 1] = fmaf(fb[kk], wv.y, acc1[c4 * 4 + 1]);
                acc1[c4 * 4 + 2] = fmaf(fb[kk], wv.z, acc1[c4 * 4 + 2]);
                acc1[c4 * 4 + 3] = fmaf(fb[kk], wv.w, acc1[c4 * 4 + 3]);
            }
        }
    }
    if (row0 < N) {
        float d = dis[row0];
        uint4* gp = (uint4*)(gb + (size_t)row0 * F2 + c0);
#pragma unroll
        for (int c8 = 0; c8 < 2; c8++) {
            uint4 o;
            o.x = pack2(acc0[c8 * 8 + 0] * d, acc0[c8 * 8 + 1] * d);
            o.y = pack2(acc0[c8 * 8 + 2] * d, acc0[c8 * 8 + 3] * d);
            o.z = pack2(acc0[c8 * 8 + 4] * d, acc0[c8 * 8 + 5] * d);
            o.w = pack2(acc0[c8 * 8 + 6] * d, acc0[c8 * 8 + 7] * d);
            gp[c8] = o;
        }
    }
    if (row0 + 64 < N) {
        float d = dis[row0 + 64];
        uint4* gp = (uint4*)(gb + (size_t)(row0 + 64) * F2 + c0);
#pragma unroll
        for (int c8 = 0; c8 < 2; c8++) {
            uint4 o;
            o.x = pack2(acc1[c8 * 8 + 0] * d, acc1[c8 * 8 + 1] * d);
            o.y = pack2(acc1[c8 * 8 + 2] * d, acc1[c8 * 8 + 3] * d);
            o.z = pack2(acc1[c8 * 8 + 4] * d, acc1[c8 * 8 + 5] * d);
            o.w = pack2(acc1[c8 * 8 + 6] * d, acc1[c8 * 8 + 7] * d);
            gp[c8] = o;
        }
    }
}

// ---------------- Aggregation 2: out(fp32) = dis[i]*(g2[i] + sum g2[src]) + b2 ----------------
// g2 row = 64 bf16 (128 B); lane owns one col (u16 load).

__global__ __launch_bounds__(256) void k_agg2(const u16* __restrict__ g,
                                              const int* __restrict__ rowptr,
                                              const int* __restrict__ adj,
                                              const float* __restrict__ dis,
                                              const float* __restrict__ b,
                                              float* __restrict__ out, int N) {
    int node = __builtin_amdgcn_readfirstlane(blockIdx.x * 4 + (threadIdx.x >> 6));
    if (node >= N) return;
    int lane = threadIdx.x & 63;
    float acc = bf1(g[(size_t)node * F2 + lane]);   // self-loop term
    int s = rowptr[node], e = rowptr[node + 1];
    int j = s;
    for (; j + 3 < e; j += 4) {
        int s0 = adj[j], s1 = adj[j + 1], s2 = adj[j + 2], s3 = adj[j + 3];
        float v0 = bf1(g[(size_t)s0 * F2 + lane]);
        float v1 = bf1(g[(size_t)s1 * F2 + lane]);
        float v2 = bf1(g[(size_t)s2 * F2 + lane]);
        float v3 = bf1(g[(size_t)s3 * F2 + lane]);
        acc += (v0 + v1) + (v2 + v3);
    }
    for (; j < e; j++) acc += bf1(g[(size_t)adj[j] * F2 + lane]);
    out[(size_t)node * F2 + lane] = fmaf(dis[node], acc, b[lane]);
}

// ---------------- launch ----------------

extern "C" void kernel_launch(void* const* d_in, const int* in_sizes, int n_in,
                              void* d_out, int out_size, void* d_ws, size_t ws_size,
                              hipStream_t stream) {
    const float* x  = (const float*)d_in[0];
    const int*   ei = (const int*)d_in[1];
    const float* W1 = (const float*)d_in[2];
    const float* b1 = (const float*)d_in[3];
    const float* W2 = (const float*)d_in[4];
    const float* b2 = (const float*)d_in[5];
    float* out = (float*)d_out;

    const int N = in_sizes[0] / F1;
    const int E = in_sizes[1] / 2;
    const int NB = (N + BSZ - 1) >> BSH;   // 196 for N=100000; must be <= 256
    const int* rowv = ei;        // sources
    const int* colv = ei + E;    // targets

    char* ws = (char*)d_ws;
    size_t off = 0;
    auto take = [&](size_t bytes) -> void* {
        void* p = ws + off;
        off += (bytes + 255) & ~(size_t)255;
        return p;
    };
    u16*   g1b     = (u16*)take((size_t)N * F1 * 2);   // 25.6 MB (bf16)
    u32*   zb      = (u32*)take((size_t)N * 64 * 4);   // 25.6 MB (bf16 packed as u32 pairs)
    u16*   g2b     = g1b;                // g1 dead after agg1 -> reuse
    u32*   ebuf    = (u32*)g1b;          // ebuf (6.4 MB) dead before gemm1 writes g1
    float* dis     = (float*)take((size_t)N * 4);
    int*   rowptr  = (int*)take((size_t)(N + 1) * 4);
    int*   adj     = (int*)take((size_t)E * 4);        // 6.4 MB
    int*   bucket_cnt  = (int*)take(256 * 4);
    int*   bucket_base = (int*)take(257 * 4);
    int*   bucket_cur  = (int*)take(256 * 4);

    hipMemsetAsync(bucket_cnt, 0, 256 * 4, stream);

    k_bhist<<<256, 256, 0, stream>>>(colv, bucket_cnt, E);
    k_bscan<<<1, 256, 0, stream>>>(bucket_cnt, bucket_base, bucket_cur, rowptr + N, NB, E);
    k_part<<<(E + 4095) / 4096, 256, 0, stream>>>(rowv, colv, bucket_cur, ebuf, E);
    k_bfill<<<NB, BSZ, 0, stream>>>(ebuf, bucket_base, rowptr, dis, adj, N);

    int tiles = (N + 127) >> 7;
    k_gemm1<<<tiles, 256, 0, stream>>>(x, W1, dis, g1b, N);
    k_agg1<<<(N + 3) / 4, 256, 0, stream>>>((const u32*)g1b, rowptr, adj, dis, b1, zb, N);
    k_gemm2<<<tiles, 256, 0, stream>>>(zb, W2, dis, g2b, N);
    k_agg2<<<(N + 3) / 4, 256, 0, stream>>>(g2b, rowptr, adj, dis, b2, out, N);
}

// Round 7
// 290.067 us; speedup vs baseline: 3.0135x; 1.2151x over previous
//
#include <hip/hip_runtime.h>

#define F1 128
#define F2 64
// bucket = 512 consecutive nodes; requires N <= 256*512 and N < 2^17 (u32 ebuf pack)
#define BSH 9
#define BSZ 512

typedef unsigned int u32;
typedef unsigned short u16;
typedef __attribute__((ext_vector_type(8))) short bf16x8;   // 8 bf16 (4 VGPRs)
typedef __attribute__((ext_vector_type(4))) float f32x4;

// bf16 helpers (manual, header-version-proof). RNE pack, shift unpack.
__device__ __forceinline__ u32 bf16rne(float f) {
    u32 u = __float_as_uint(f);
    return (u + 0x7FFFu + ((u >> 16) & 1u)) >> 16;
}
__device__ __forceinline__ u32 pack2(float lo, float hi) {
    return bf16rne(lo) | (bf16rne(hi) << 16);
}
__device__ __forceinline__ float bflo(u32 u) { return __uint_as_float(u << 16); }
__device__ __forceinline__ float bfhi(u32 u) { return __uint_as_float(u & 0xFFFF0000u); }
__device__ __forceinline__ float bf1(u16 u) { return __uint_as_float((u32)u << 16); }

// ---------------- CSR build (bucketed, LDS atomics) ----------------

__global__ __launch_bounds__(256) void k_bhist(const int* __restrict__ colv,
                                               int* __restrict__ bucket_cnt, int E) {
    __shared__ int l[256];
    int t = threadIdx.x;
    l[t] = 0;
    __syncthreads();
    for (int e = blockIdx.x * blockDim.x + t; e < E; e += gridDim.x * blockDim.x)
        atomicAdd(&l[colv[e] >> BSH], 1);
    __syncthreads();
    if (l[t]) atomicAdd(&bucket_cnt[t], l[t]);
}

__global__ __launch_bounds__(256) void k_bscan(const int* __restrict__ bucket_cnt,
                                               int* __restrict__ bucket_base,
                                               int* __restrict__ bucket_cur,
                                               int* __restrict__ rowptr_last,
                                               int NB, int E) {
    __shared__ int s[256];
    int t = threadIdx.x;
    int v = (t < NB) ? bucket_cnt[t] : 0;
    s[t] = v;
    __syncthreads();
    for (int d = 1; d < 256; d <<= 1) {
        int u = (t >= d) ? s[t - d] : 0;
        __syncthreads();
        s[t] += u;
        __syncthreads();
    }
    int excl = s[t] - v;
    if (t < NB) { bucket_base[t] = excl; bucket_cur[t] = excl; }
    if (t == NB - 1) bucket_base[NB] = s[t];
    if (t == 0) *rowptr_last = E;
}

// Stage 4096 edges in registers, reserve per-bucket runs with ONE global atomic
// per bucket, write packed (c_local<<17 | row) u32 bucket-major.
__global__ __launch_bounds__(256) void k_part(const int* __restrict__ rowv,
                                              const int* __restrict__ colv,
                                              int* __restrict__ bucket_cur,
                                              u32* __restrict__ ebuf, int E) {
    __shared__ int lcnt[256], lbase[256], loff[256];
    int t = threadIdx.x;
    lcnt[t] = 0; loff[t] = 0;
    __syncthreads();
    int rows[16], cols[16];
    int e0 = blockIdx.x * 4096;
#pragma unroll
    for (int it = 0; it < 16; it++) {
        int e = e0 + it * 256 + t;
        bool v = e < E;
        cols[it] = v ? colv[e] : -1;
        rows[it] = v ? rowv[e] : 0;
        if (v) atomicAdd(&lcnt[cols[it] >> BSH], 1);
    }
    __syncthreads();
    if (lcnt[t]) lbase[t] = atomicAdd(&bucket_cur[t], lcnt[t]);
    __syncthreads();
#pragma unroll
    for (int it = 0; it < 16; it++) {
        if (cols[it] >= 0) {
            int b = cols[it] >> BSH;
            int p = lbase[b] + atomicAdd(&loff[b], 1);
            ebuf[p] = ((u32)(cols[it] & (BSZ - 1)) << 17) | (u32)rows[it];
        }
    }
}

// One block per bucket: per-node counts + scan + placement all via LDS.
__global__ __launch_bounds__(512) void k_bfill(const u32* __restrict__ ebuf,
                                               const int* __restrict__ bucket_base,
                                               int* __restrict__ rowptr,
                                               float* __restrict__ dis,
                                               int* __restrict__ adj, int N) {
    __shared__ int cnt[BSZ], scn[BSZ], cur[BSZ];
    int t = threadIdx.x;
    int b = blockIdx.x;
    int e0 = bucket_base[b], e1 = bucket_base[b + 1];
    cnt[t] = 0;
    __syncthreads();
    for (int i = e0 + t; i < e1; i += BSZ)
        atomicAdd(&cnt[ebuf[i] >> 17], 1);
    __syncthreads();
    scn[t] = cnt[t];
    __syncthreads();
    for (int d = 1; d < BSZ; d <<= 1) {
        int u = (t >= d) ? scn[t - d] : 0;
        __syncthreads();
        scn[t] += u;
        __syncthreads();
    }
    int excl = scn[t] - cnt[t];
    cur[t] = excl;
    int node = (b << BSH) + t;
    if (node < N) {
        rowptr[node] = e0 + excl;
        dis[node] = rsqrtf((float)(cnt[t] + 1));   // +1 self loop
    }
    __syncthreads();
    for (int i = e0 + t; i < e1; i += BSZ) {
        u32 p = ebuf[i];
        int c = p >> 17;
        int r = (int)(p & 0x1FFFFu);
        int pos = atomicAdd(&cur[c], 1);
        adj[e0 + pos] = r;
    }
}

// ---------------- W prep: fp32 W[K][C] -> bf16 B-frag order [kb][nb][lane][j] ----------------
// Frag layout for mfma_f32_16x16x32_bf16 B-operand: n = lane&15, k = (lane>>4)*8 + j.
// One thread per (kb, nb, lane): 8 column-strided fp32 reads -> one uint4 store.

__global__ __launch_bounds__(256) void k_wprep(const float* __restrict__ W,
                                               uint4* __restrict__ wf, int NBc) {
    int t = blockIdx.x * 256 + threadIdx.x;
    int total = 4 * NBc * 64;
    if (t >= total) return;
    int lane = t & 63;
    int rem = t >> 6;
    int nb = rem % NBc;
    int kb = rem / NBc;
    int C = NBc * 16;
    int col = nb * 16 + (lane & 15);
    int krow = kb * 32 + (lane >> 4) * 8;
    u32 w[4];
#pragma unroll
    for (int p = 0; p < 4; p++) {
        float lo = W[(size_t)(krow + 2 * p) * C + col];
        float hi = W[(size_t)(krow + 2 * p + 1) * C + col];
        w[p] = pack2(lo, hi);
    }
    wf[t] = make_uint4(w[0], w[1], w[2], w[3]);
}

// ---------------- GEMM 1 (MFMA): g1(bf16) = dis[row] * (x @ W1) ----------------
// Wave = 16 rows x 128 cols: 8 n-tiles x 4 k-blocks = 32 mfma_f32_16x16x32_bf16.
// A: per-lane 8 fp32 from x row (lane&15), k=quad*8.., RNE-packed to bf16.
// B: coalesced dwordx4 from pre-arranged w1f (L2-hot). No LDS, no barriers.

__global__ __launch_bounds__(256, 4) void k_gemm1(const float* __restrict__ x,
                                                  const uint4* __restrict__ w1f,
                                                  const float* __restrict__ dis,
                                                  u16* __restrict__ gb, int N) {
    int lane = threadIdx.x & 63;
    int wave = threadIdx.x >> 6;
    int m = lane & 15, quad = lane >> 4;
    int row0 = blockIdx.x * 64 + wave * 16;
    int arow = min(row0 + m, N - 1);
    const float* xr = x + (size_t)arow * F1 + quad * 8;
    bf16x8 a[4];
#pragma unroll
    for (int kb = 0; kb < 4; kb++) {
        float4 lo = *(const float4*)(xr + kb * 32);
        float4 hi = *(const float4*)(xr + kb * 32 + 4);
        a[kb][0] = (short)bf16rne(lo.x); a[kb][1] = (short)bf16rne(lo.y);
        a[kb][2] = (short)bf16rne(lo.z); a[kb][3] = (short)bf16rne(lo.w);
        a[kb][4] = (short)bf16rne(hi.x); a[kb][5] = (short)bf16rne(hi.y);
        a[kb][6] = (short)bf16rne(hi.z); a[kb][7] = (short)bf16rne(hi.w);
    }
    f32x4 acc[8];
#pragma unroll
    for (int nb = 0; nb < 8; nb++) acc[nb] = (f32x4)(0.0f);
#pragma unroll
    for (int nb = 0; nb < 8; nb++) {
#pragma unroll
        for (int kb = 0; kb < 4; kb++) {
            uint4 braw = w1f[(kb * 8 + nb) * 64 + lane];
            bf16x8 bf = *(bf16x8*)&braw;
            acc[nb] = __builtin_amdgcn_mfma_f32_16x16x32_bf16(a[kb], bf, acc[nb], 0, 0, 0);
        }
    }
    // epilogue: C layout col = lane&15, row = quad*4 + reg
    float dv[4];
    int rbase = row0 + quad * 4;
#pragma unroll
    for (int reg = 0; reg < 4; reg++) dv[reg] = dis[min(rbase + reg, N - 1)];
#pragma unroll
    for (int reg = 0; reg < 4; reg++) {
        int r = rbase + reg;
        if (r < N) {
            u16* gr = gb + (size_t)r * F1 + m;
#pragma unroll
            for (int nb = 0; nb < 8; nb++)
                gr[nb * 16] = (u16)bf16rne(acc[nb][reg] * dv[reg]);
        }
    }
}

// ---------------- Aggregation 1: z(bf16) = relu(dis[i]*(g1[i] + sum g1[src]) + b1) ----------------

__global__ __launch_bounds__(256) void k_agg1(const u32* __restrict__ g1,
                                              const int* __restrict__ rowptr,
                                              const int* __restrict__ adj,
                                              const float* __restrict__ dis,
                                              const float* __restrict__ b,
                                              u32* __restrict__ z, int N) {
    int node = __builtin_amdgcn_readfirstlane(blockIdx.x * 4 + (threadIdx.x >> 6));
    if (node >= N) return;
    int lane = threadIdx.x & 63;
    u32 sv = g1[(size_t)node * 64 + lane];   // self-loop term
    float ax = bflo(sv), ay = bfhi(sv);
    int s = rowptr[node], e = rowptr[node + 1];
    int j = s;
    for (; j + 3 < e; j += 4) {
        int s0 = adj[j], s1 = adj[j + 1], s2 = adj[j + 2], s3 = adj[j + 3];
        u32 v0 = g1[(size_t)s0 * 64 + lane];
        u32 v1 = g1[(size_t)s1 * 64 + lane];
        u32 v2 = g1[(size_t)s2 * 64 + lane];
        u32 v3 = g1[(size_t)s3 * 64 + lane];
        ax += (bflo(v0) + bflo(v1)) + (bflo(v2) + bflo(v3));
        ay += (bfhi(v0) + bfhi(v1)) + (bfhi(v2) + bfhi(v3));
    }
    for (; j < e; j++) {
        u32 v = g1[(size_t)adj[j] * 64 + lane];
        ax += bflo(v); ay += bfhi(v);
    }
    float d = dis[node];
    float2 bb = ((const float2*)b)[lane];
    float ox = fmaxf(fmaf(d, ax, bb.x), 0.0f);
    float oy = fmaxf(fmaf(d, ay, bb.y), 0.0f);
    z[(size_t)node * 64 + lane] = pack2(ox, oy);
}

// ---------------- GEMM 2 (MFMA): g2(bf16) = dis[row] * (z @ W2) ----------------
// Wave = 16 rows x 64 cols: 4 n-tiles x 4 k-blocks = 16 MFMAs. z already bf16:
// A-frag is one dwordx4 per k-block straight from z.

__global__ __launch_bounds__(256, 4) void k_gemm2(const u32* __restrict__ z,
                                                  const uint4* __restrict__ w2f,
                                                  const float* __restrict__ dis,
                                                  u16* __restrict__ gb, int N) {
    int lane = threadIdx.x & 63;
    int wave = threadIdx.x >> 6;
    int m = lane & 15, quad = lane >> 4;
    int row0 = blockIdx.x * 64 + wave * 16;
    int arow = min(row0 + m, N - 1);
    const u32* zr = z + (size_t)arow * 64 + quad * 4;
    bf16x8 a[4];
#pragma unroll
    for (int kb = 0; kb < 4; kb++) {
        uint4 za = *(const uint4*)(zr + kb * 16);
        a[kb] = *(bf16x8*)&za;
    }
    f32x4 acc[4];
#pragma unroll
    for (int nb = 0; nb < 4; nb++) acc[nb] = (f32x4)(0.0f);
#pragma unroll
    for (int nb = 0; nb < 4; nb++) {
#pragma unroll
        for (int kb = 0; kb < 4; kb++) {
            uint4 braw = w2f[(kb * 4 + nb) * 64 + lane];
            bf16x8 bf = *(bf16x8*)&braw;
            acc[nb] = __builtin_amdgcn_mfma_f32_16x16x32_bf16(a[kb], bf, acc[nb], 0, 0, 0);
        }
    }
    float dv[4];
    int rbase = row0 + quad * 4;
#pragma unroll
    for (int reg = 0; reg < 4; reg++) dv[reg] = dis[min(rbase + reg, N - 1)];
#pragma unroll
    for (int reg = 0; reg < 4; reg++) {
        int r = rbase + reg;
        if (r < N) {
            u16* gr = gb + (size_t)r * F2 + m;
#pragma unroll
            for (int nb = 0; nb < 4; nb++)
                gr[nb * 16] = (u16)bf16rne(acc[nb][reg] * dv[reg]);
        }
    }
}

// ---------------- Aggregation 2: out(fp32) = dis[i]*(g2[i] + sum g2[src]) + b2 ----------------

__global__ __launch_bounds__(256) void k_agg2(const u16* __restrict__ g,
                                              const int* __restrict__ rowptr,
                                              const int* __restrict__ adj,
                                              const float* __restrict__ dis,
                                              const float* __restrict__ b,
                                              float* __restrict__ out, int N) {
    int node = __builtin_amdgcn_readfirstlane(blockIdx.x * 4 + (threadIdx.x >> 6));
    if (node >= N) return;
    int lane = threadIdx.x & 63;
    float acc = bf1(g[(size_t)node * F2 + lane]);   // self-loop term
    int s = rowptr[node], e = rowptr[node + 1];
    int j = s;
    for (; j + 3 < e; j += 4) {
        int s0 = adj[j], s1 = adj[j + 1], s2 = adj[j + 2], s3 = adj[j + 3];
        float v0 = bf1(g[(size_t)s0 * F2 + lane]);
        float v1 = bf1(g[(size_t)s1 * F2 + lane]);
        float v2 = bf1(g[(size_t)s2 * F2 + lane]);
        float v3 = bf1(g[(size_t)s3 * F2 + lane]);
        acc += (v0 + v1) + (v2 + v3);
    }
    for (; j < e; j++) acc += bf1(g[(size_t)adj[j] * F2 + lane]);
    out[(size_t)node * F2 + lane] = fmaf(dis[node], acc, b[lane]);
}

// ---------------- launch ----------------

extern "C" void kernel_launch(void* const* d_in, const int* in_sizes, int n_in,
                              void* d_out, int out_size, void* d_ws, size_t ws_size,
                              hipStream_t stream) {
    const float* x  = (const float*)d_in[0];
    const int*   ei = (const int*)d_in[1];
    const float* W1 = (const float*)d_in[2];
    const float* b1 = (const float*)d_in[3];
    const float* W2 = (const float*)d_in[4];
    const float* b2 = (const float*)d_in[5];
    float* out = (float*)d_out;

    const int N = in_sizes[0] / F1;
    const int E = in_sizes[1] / 2;
    const int NB = (N + BSZ - 1) >> BSH;   // 196 for N=100000; must be <= 256
    const int* rowv = ei;        // sources
    const int* colv = ei + E;    // targets

    char* ws = (char*)d_ws;
    size_t off = 0;
    auto take = [&](size_t bytes) -> void* {
        void* p = ws + off;
        off += (bytes + 255) & ~(size_t)255;
        return p;
    };
    u16*   g1b     = (u16*)take((size_t)N * F1 * 2);   // 25.6 MB (bf16)
    u32*   zb      = (u32*)take((size_t)N * 64 * 4);   // 25.6 MB (bf16 packed)
    u16*   g2b     = g1b;                // g1 dead after agg1 -> reuse
    u32*   ebuf    = (u32*)g1b;          // ebuf (6.4 MB) dead before gemm1 writes g1
    float* dis     = (float*)take((size_t)N * 4);
    int*   rowptr  = (int*)take((size_t)(N + 1) * 4);
    int*   adj     = (int*)take((size_t)E * 4);        // 6.4 MB
    uint4* w1f     = (uint4*)take(4 * 8 * 64 * 16);    // 32 KB bf16 frag-order W1
    uint4* w2f     = (uint4*)take(4 * 4 * 64 * 16);    // 16 KB bf16 frag-order W2
    int*   bucket_cnt  = (int*)take(256 * 4);
    int*   bucket_base = (int*)take(257 * 4);
    int*   bucket_cur  = (int*)take(256 * 4);

    hipMemsetAsync(bucket_cnt, 0, 256 * 4, stream);

    k_wprep<<<8, 256, 0, stream>>>(W1, w1f, 8);
    k_wprep<<<4, 256, 0, stream>>>(W2, w2f, 4);

    k_bhist<<<256, 256, 0, stream>>>(colv, bucket_cnt, E);
    k_bscan<<<1, 256, 0, stream>>>(bucket_cnt, bucket_base, bucket_cur, rowptr + N, NB, E);
    k_part<<<(E + 4095) / 4096, 256, 0, stream>>>(rowv, colv, bucket_cur, ebuf, E);
    k_bfill<<<NB, BSZ, 0, stream>>>(ebuf, bucket_base, rowptr, dis, adj, N);

    int gblocks = (N + 63) / 64;
    k_gemm1<<<gblocks, 256, 0, stream>>>(x, w1f, dis, g1b, N);
    k_agg1<<<(N + 3) / 4, 256, 0, stream>>>((const u32*)g1b, rowptr, adj, dis, b1, zb, N);
    k_gemm2<<<gblocks, 256, 0, stream>>>(zb, w2f, dis, g2b, N);
    k_agg2<<<(N + 3) / 4, 256, 0, stream>>>(g2b, rowptr, adj, dis, b2, out, N);
}

// Round 8
// 286.225 us; speedup vs baseline: 3.0539x; 1.0134x over previous
//
#include <hip/hip_runtime.h>

#define F1 128
#define F2 64
// bucket = 512 consecutive nodes; requires N <= 256*512 and N < 2^17 (u32 ebuf pack)
#define BSH 9
#define BSZ 512

typedef unsigned int u32;
typedef unsigned short u16;
typedef __attribute__((ext_vector_type(8))) short bf16x8;   // 8 bf16 (4 VGPRs)
typedef __attribute__((ext_vector_type(4))) float f32x4;

// bf16 helpers (manual, header-version-proof). RNE pack, shift unpack.
__device__ __forceinline__ u32 bf16rne(float f) {
    u32 u = __float_as_uint(f);
    return (u + 0x7FFFu + ((u >> 16) & 1u)) >> 16;
}
__device__ __forceinline__ u32 pack2(float lo, float hi) {
    return bf16rne(lo) | (bf16rne(hi) << 16);
}
__device__ __forceinline__ float bflo(u32 u) { return __uint_as_float(u << 16); }
__device__ __forceinline__ float bfhi(u32 u) { return __uint_as_float(u & 0xFFFF0000u); }

__device__ __forceinline__ void acc8(float* ax, uint4 v) {
    ax[0] += bflo(v.x); ax[1] += bfhi(v.x);
    ax[2] += bflo(v.y); ax[3] += bfhi(v.y);
    ax[4] += bflo(v.z); ax[5] += bfhi(v.z);
    ax[6] += bflo(v.w); ax[7] += bfhi(v.w);
}

// ---------------- CSR build (bucketed, LDS atomics) ----------------

__global__ __launch_bounds__(256) void k_bhist(const int* __restrict__ colv,
                                               int* __restrict__ bucket_cnt, int E) {
    __shared__ int l[256];
    int t = threadIdx.x;
    l[t] = 0;
    __syncthreads();
    for (int e = blockIdx.x * blockDim.x + t; e < E; e += gridDim.x * blockDim.x)
        atomicAdd(&l[colv[e] >> BSH], 1);
    __syncthreads();
    if (l[t]) atomicAdd(&bucket_cnt[t], l[t]);
}

__global__ __launch_bounds__(256) void k_bscan(const int* __restrict__ bucket_cnt,
                                               int* __restrict__ bucket_base,
                                               int* __restrict__ bucket_cur,
                                               int* __restrict__ rowptr_last,
                                               int NB, int E) {
    __shared__ int s[256];
    int t = threadIdx.x;
    int v = (t < NB) ? bucket_cnt[t] : 0;
    s[t] = v;
    __syncthreads();
    for (int d = 1; d < 256; d <<= 1) {
        int u = (t >= d) ? s[t - d] : 0;
        __syncthreads();
        s[t] += u;
        __syncthreads();
    }
    int excl = s[t] - v;
    if (t < NB) { bucket_base[t] = excl; bucket_cur[t] = excl; }
    if (t == NB - 1) bucket_base[NB] = s[t];
    if (t == 0) *rowptr_last = E;
}

// Stage 4096 edges in registers, reserve per-bucket runs with ONE global atomic
// per bucket, write packed (c_local<<17 | row) u32 bucket-major.
__global__ __launch_bounds__(256) void k_part(const int* __restrict__ rowv,
                                              const int* __restrict__ colv,
                                              int* __restrict__ bucket_cur,
                                              u32* __restrict__ ebuf, int E) {
    __shared__ int lcnt[256], lbase[256], loff[256];
    int t = threadIdx.x;
    lcnt[t] = 0; loff[t] = 0;
    __syncthreads();
    int rows[16], cols[16];
    int e0 = blockIdx.x * 4096;
#pragma unroll
    for (int it = 0; it < 16; it++) {
        int e = e0 + it * 256 + t;
        bool v = e < E;
        cols[it] = v ? colv[e] : -1;
        rows[it] = v ? rowv[e] : 0;
        if (v) atomicAdd(&lcnt[cols[it] >> BSH], 1);
    }
    __syncthreads();
    if (lcnt[t]) lbase[t] = atomicAdd(&bucket_cur[t], lcnt[t]);
    __syncthreads();
#pragma unroll
    for (int it = 0; it < 16; it++) {
        if (cols[it] >= 0) {
            int b = cols[it] >> BSH;
            int p = lbase[b] + atomicAdd(&loff[b], 1);
            ebuf[p] = ((u32)(cols[it] & (BSZ - 1)) << 17) | (u32)rows[it];
        }
    }
}

// One block per bucket: per-node counts + scan + placement all via LDS.
__global__ __launch_bounds__(512) void k_bfill(const u32* __restrict__ ebuf,
                                               const int* __restrict__ bucket_base,
                                               int* __restrict__ rowptr,
                                               float* __restrict__ dis,
                                               int* __restrict__ adj, int N) {
    __shared__ int cnt[BSZ], scn[BSZ], cur[BSZ];
    int t = threadIdx.x;
    int b = blockIdx.x;
    int e0 = bucket_base[b], e1 = bucket_base[b + 1];
    cnt[t] = 0;
    __syncthreads();
    for (int i = e0 + t; i < e1; i += BSZ)
        atomicAdd(&cnt[ebuf[i] >> 17], 1);
    __syncthreads();
    scn[t] = cnt[t];
    __syncthreads();
    for (int d = 1; d < BSZ; d <<= 1) {
        int u = (t >= d) ? scn[t - d] : 0;
        __syncthreads();
        scn[t] += u;
        __syncthreads();
    }
    int excl = scn[t] - cnt[t];
    cur[t] = excl;
    int node = (b << BSH) + t;
    if (node < N) {
        rowptr[node] = e0 + excl;
        dis[node] = rsqrtf((float)(cnt[t] + 1));   // +1 self loop
    }
    __syncthreads();
    for (int i = e0 + t; i < e1; i += BSZ) {
        u32 p = ebuf[i];
        int c = p >> 17;
        int r = (int)(p & 0x1FFFFu);
        int pos = atomicAdd(&cur[c], 1);
        adj[e0 + pos] = r;
    }
}

// ---------------- W prep: fp32 W[K][C] -> bf16 B-frag order [kb][nb][lane][j] ----------------
// Frag layout for mfma_f32_16x16x32_bf16 B-operand: n = lane&15, k = (lane>>4)*8 + j.
// Blocks 0-7: W1 (NBc=8). Blocks 8-11: W2 (NBc=4).

__device__ __forceinline__ void wprep_do(const float* __restrict__ W,
                                         uint4* __restrict__ wf, int NBc, int t) {
    int lane = t & 63;
    int rem = t >> 6;
    int nb = rem % NBc;
    int kb = rem / NBc;
    int C = NBc * 16;
    int col = nb * 16 + (lane & 15);
    int krow = kb * 32 + (lane >> 4) * 8;
    u32 w[4];
#pragma unroll
    for (int p = 0; p < 4; p++) {
        float lo = W[(size_t)(krow + 2 * p) * C + col];
        float hi = W[(size_t)(krow + 2 * p + 1) * C + col];
        w[p] = pack2(lo, hi);
    }
    wf[t] = make_uint4(w[0], w[1], w[2], w[3]);
}

__global__ __launch_bounds__(256) void k_wprep(const float* __restrict__ W1,
                                               const float* __restrict__ W2,
                                               uint4* __restrict__ w1f,
                                               uint4* __restrict__ w2f) {
    int blk = blockIdx.x;
    if (blk < 8) wprep_do(W1, w1f, 8, blk * 256 + threadIdx.x);
    else         wprep_do(W2, w2f, 4, (blk - 8) * 256 + threadIdx.x);
}

// ---------------- GEMM 1 (MFMA): g1(bf16) = dis[row] * (x @ W1) ----------------

__global__ __launch_bounds__(256, 4) void k_gemm1(const float* __restrict__ x,
                                                  const uint4* __restrict__ w1f,
                                                  const float* __restrict__ dis,
                                                  u16* __restrict__ gb, int N) {
    int lane = threadIdx.x & 63;
    int wave = threadIdx.x >> 6;
    int m = lane & 15, quad = lane >> 4;
    int row0 = blockIdx.x * 64 + wave * 16;
    int arow = min(row0 + m, N - 1);
    const float* xr = x + (size_t)arow * F1 + quad * 8;
    bf16x8 a[4];
#pragma unroll
    for (int kb = 0; kb < 4; kb++) {
        float4 lo = *(const float4*)(xr + kb * 32);
        float4 hi = *(const float4*)(xr + kb * 32 + 4);
        a[kb][0] = (short)bf16rne(lo.x); a[kb][1] = (short)bf16rne(lo.y);
        a[kb][2] = (short)bf16rne(lo.z); a[kb][3] = (short)bf16rne(lo.w);
        a[kb][4] = (short)bf16rne(hi.x); a[kb][5] = (short)bf16rne(hi.y);
        a[kb][6] = (short)bf16rne(hi.z); a[kb][7] = (short)bf16rne(hi.w);
    }
    f32x4 acc[8];
#pragma unroll
    for (int nb = 0; nb < 8; nb++) acc[nb] = (f32x4)(0.0f);
#pragma unroll
    for (int nb = 0; nb < 8; nb++) {
#pragma unroll
        for (int kb = 0; kb < 4; kb++) {
            uint4 braw = w1f[(kb * 8 + nb) * 64 + lane];
            bf16x8 bf = *(bf16x8*)&braw;
            acc[nb] = __builtin_amdgcn_mfma_f32_16x16x32_bf16(a[kb], bf, acc[nb], 0, 0, 0);
        }
    }
    // epilogue: C layout col = lane&15, row = quad*4 + reg
    float dv[4];
    int rbase = row0 + quad * 4;
#pragma unroll
    for (int reg = 0; reg < 4; reg++) dv[reg] = dis[min(rbase + reg, N - 1)];
#pragma unroll
    for (int reg = 0; reg < 4; reg++) {
        int r = rbase + reg;
        if (r < N) {
            u16* gr = gb + (size_t)r * F1 + m;
#pragma unroll
            for (int nb = 0; nb < 8; nb++)
                gr[nb * 16] = (u16)bf16rne(acc[nb][reg] * dv[reg]);
        }
    }
}

// ---------------- Aggregation 1: z(bf16) = relu(dis[i]*(g1[i] + sum g1[src]) + b1) ----------------
// Wave = 1 node. 4 lane-groups of 16; each group gathers one full 256B source row
// (16 lanes x uint4). 4 edges per load instruction, unroll 2 -> 8 in flight.
// Cross-group reduce: shfl_xor 16, 32.

__global__ __launch_bounds__(256) void k_agg1(const uint4* __restrict__ g1,
                                              const int* __restrict__ rowptr,
                                              const int* __restrict__ adj,
                                              const float* __restrict__ dis,
                                              const float* __restrict__ b,
                                              uint4* __restrict__ z, int N) {
    int node = __builtin_amdgcn_readfirstlane(blockIdx.x * 4 + (threadIdx.x >> 6));
    if (node >= N) return;
    int lane = threadIdx.x & 63;
    int grp = lane >> 4;        // 0..3
    int sub = lane & 15;        // col chunk: cols [8*sub, 8*sub+8)
    float ax[8];
#pragma unroll
    for (int i = 0; i < 8; i++) ax[i] = 0.0f;
    if (grp == 0) acc8(ax, g1[(size_t)node * 16 + sub]);   // self-loop term, once
    int s = rowptr[node], e = rowptr[node + 1];
    int j = s;
    for (; j + 7 < e; j += 8) {
        int s0 = adj[j + grp];
        int s1 = adj[j + 4 + grp];
        uint4 v0 = g1[(size_t)s0 * 16 + sub];
        uint4 v1 = g1[(size_t)s1 * 16 + sub];
        acc8(ax, v0);
        acc8(ax, v1);
    }
    for (; j < e; j += 4) {
        int idx = j + grp;
        if (idx < e) acc8(ax, g1[(size_t)adj[idx] * 16 + sub]);
    }
#pragma unroll
    for (int i = 0; i < 8; i++) {
        ax[i] += __shfl_xor(ax[i], 16);
        ax[i] += __shfl_xor(ax[i], 32);
    }
    if (grp == 0) {
        float d = dis[node];
        float4 b0 = *(const float4*)(b + 8 * sub);
        float4 b1 = *(const float4*)(b + 8 * sub + 4);
        float o[8];
        o[0] = fmaxf(fmaf(d, ax[0], b0.x), 0.0f);
        o[1] = fmaxf(fmaf(d, ax[1], b0.y), 0.0f);
        o[2] = fmaxf(fmaf(d, ax[2], b0.z), 0.0f);
        o[3] = fmaxf(fmaf(d, ax[3], b0.w), 0.0f);
        o[4] = fmaxf(fmaf(d, ax[4], b1.x), 0.0f);
        o[5] = fmaxf(fmaf(d, ax[5], b1.y), 0.0f);
        o[6] = fmaxf(fmaf(d, ax[6], b1.z), 0.0f);
        o[7] = fmaxf(fmaf(d, ax[7], b1.w), 0.0f);
        uint4 ov;
        ov.x = pack2(o[0], o[1]); ov.y = pack2(o[2], o[3]);
        ov.z = pack2(o[4], o[5]); ov.w = pack2(o[6], o[7]);
        z[(size_t)node * 16 + sub] = ov;
    }
}

// ---------------- GEMM 2 (MFMA): g2(bf16) = dis[row] * (z @ W2) ----------------

__global__ __launch_bounds__(256, 4) void k_gemm2(const u32* __restrict__ z,
                                                  const uint4* __restrict__ w2f,
                                                  const float* __restrict__ dis,
                                                  u16* __restrict__ gb, int N) {
    int lane = threadIdx.x & 63;
    int wave = threadIdx.x >> 6;
    int m = lane & 15, quad = lane >> 4;
    int row0 = blockIdx.x * 64 + wave * 16;
    int arow = min(row0 + m, N - 1);
    const u32* zr = z + (size_t)arow * 64 + quad * 4;
    bf16x8 a[4];
#pragma unroll
    for (int kb = 0; kb < 4; kb++) {
        uint4 za = *(const uint4*)(zr + kb * 16);
        a[kb] = *(bf16x8*)&za;
    }
    f32x4 acc[4];
#pragma unroll
    for (int nb = 0; nb < 4; nb++) acc[nb] = (f32x4)(0.0f);
#pragma unroll
    for (int nb = 0; nb < 4; nb++) {
#pragma unroll
        for (int kb = 0; kb < 4; kb++) {
            uint4 braw = w2f[(kb * 4 + nb) * 64 + lane];
            bf16x8 bf = *(bf16x8*)&braw;
            acc[nb] = __builtin_amdgcn_mfma_f32_16x16x32_bf16(a[kb], bf, acc[nb], 0, 0, 0);
        }
    }
    float dv[4];
    int rbase = row0 + quad * 4;
#pragma unroll
    for (int reg = 0; reg < 4; reg++) dv[reg] = dis[min(rbase + reg, N - 1)];
#pragma unroll
    for (int reg = 0; reg < 4; reg++) {
        int r = rbase + reg;
        if (r < N) {
            u16* gr = gb + (size_t)r * F2 + m;
#pragma unroll
            for (int nb = 0; nb < 4; nb++)
                gr[nb * 16] = (u16)bf16rne(acc[nb][reg] * dv[reg]);
        }
    }
}

// ---------------- Aggregation 2: out(fp32) = dis[i]*(g2[i] + sum g2[src]) + b2 ----------------
// Wave = 1 node. 8 lane-groups of 8; each group gathers one 128B source row.
// 8 edges per load instruction. Reduce: shfl_xor 8, 16, 32.

__global__ __launch_bounds__(256) void k_agg2(const uint4* __restrict__ g,
                                              const int* __restrict__ rowptr,
                                              const int* __restrict__ adj,
                                              const float* __restrict__ dis,
                                              const float* __restrict__ b,
                                              float* __restrict__ out, int N) {
    int node = __builtin_amdgcn_readfirstlane(blockIdx.x * 4 + (threadIdx.x >> 6));
    if (node >= N) return;
    int lane = threadIdx.x & 63;
    int grp = lane >> 3;        // 0..7
    int sub = lane & 7;         // col chunk: cols [8*sub, 8*sub+8)
    float ax[8];
#pragma unroll
    for (int i = 0; i < 8; i++) ax[i] = 0.0f;
    if (grp == 0) acc8(ax, g[(size_t)node * 8 + sub]);   // self-loop term
    int s = rowptr[node], e = rowptr[node + 1];
    int j = s;
    for (; j + 15 < e; j += 16) {
        int s0 = adj[j + grp];
        int s1 = adj[j + 8 + grp];
        uint4 v0 = g[(size_t)s0 * 8 + sub];
        uint4 v1 = g[(size_t)s1 * 8 + sub];
        acc8(ax, v0);
        acc8(ax, v1);
    }
    for (; j < e; j += 8) {
        int idx = j + grp;
        if (idx < e) acc8(ax, g[(size_t)adj[idx] * 8 + sub]);
    }
#pragma unroll
    for (int i = 0; i < 8; i++) {
        ax[i] += __shfl_xor(ax[i], 8);
        ax[i] += __shfl_xor(ax[i], 16);
        ax[i] += __shfl_xor(ax[i], 32);
    }
    if (grp == 0) {
        float d = dis[node];
        float4 b0 = *(const float4*)(b + 8 * sub);
        float4 b1 = *(const float4*)(b + 8 * sub + 4);
        float4 o0, o1;
        o0.x = fmaf(d, ax[0], b0.x); o0.y = fmaf(d, ax[1], b0.y);
        o0.z = fmaf(d, ax[2], b0.z); o0.w = fmaf(d, ax[3], b0.w);
        o1.x = fmaf(d, ax[4], b1.x); o1.y = fmaf(d, ax[5], b1.y);
        o1.z = fmaf(d, ax[6], b1.z); o1.w = fmaf(d, ax[7], b1.w);
        float4* op = (float4*)(out + (size_t)node * F2 + 8 * sub);
        op[0] = o0;
        op[1] = o1;
    }
}

// ---------------- launch ----------------

extern "C" void kernel_launch(void* const* d_in, const int* in_sizes, int n_in,
                              void* d_out, int out_size, void* d_ws, size_t ws_size,
                              hipStream_t stream) {
    const float* x  = (const float*)d_in[0];
    const int*   ei = (const int*)d_in[1];
    const float* W1 = (const float*)d_in[2];
    const float* b1 = (const float*)d_in[3];
    const float* W2 = (const float*)d_in[4];
    const float* b2 = (const float*)d_in[5];
    float* out = (float*)d_out;

    const int N = in_sizes[0] / F1;
    const int E = in_sizes[1] / 2;
    const int NB = (N + BSZ - 1) >> BSH;   // 196 for N=100000; must be <= 256
    const int* rowv = ei;        // sources
    const int* colv = ei + E;    // targets

    char* ws = (char*)d_ws;
    size_t off = 0;
    auto take = [&](size_t bytes) -> void* {
        void* p = ws + off;
        off += (bytes + 255) & ~(size_t)255;
        return p;
    };
    u16*   g1b     = (u16*)take((size_t)N * F1 * 2);   // 25.6 MB (bf16)
    u32*   zb      = (u32*)take((size_t)N * 64 * 4);   // 25.6 MB (bf16 packed)
    u16*   g2b     = g1b;                // g1 dead after agg1 -> reuse
    u32*   ebuf    = (u32*)g1b;          // ebuf (6.4 MB) dead before gemm1 writes g1
    float* dis     = (float*)take((size_t)N * 4);
    int*   rowptr  = (int*)take((size_t)(N + 1) * 4);
    int*   adj     = (int*)take((size_t)E * 4);        // 6.4 MB
    uint4* w1f     = (uint4*)take(4 * 8 * 64 * 16);    // 32 KB bf16 frag-order W1
    uint4* w2f     = (uint4*)take(4 * 4 * 64 * 16);    // 16 KB bf16 frag-order W2
    int*   bucket_cnt  = (int*)take(256 * 4);
    int*   bucket_base = (int*)take(257 * 4);
    int*   bucket_cur  = (int*)take(256 * 4);

    hipMemsetAsync(bucket_cnt, 0, 256 * 4, stream);

    k_wprep<<<12, 256, 0, stream>>>(W1, W2, w1f, w2f);

    k_bhist<<<256, 256, 0, stream>>>(colv, bucket_cnt, E);
    k_bscan<<<1, 256, 0, stream>>>(bucket_cnt, bucket_base, bucket_cur, rowptr + N, NB, E);
    k_part<<<(E + 4095) / 4096, 256, 0, stream>>>(rowv, colv, bucket_cur, ebuf, E);
    k_bfill<<<NB, BSZ, 0, stream>>>(ebuf, bucket_base, rowptr, dis, adj, N);

    int gblocks = (N + 63) / 64;
    k_gemm1<<<gblocks, 256, 0, stream>>>(x, w1f, dis, g1b, N);
    k_agg1<<<(N + 3) / 4, 256, 0, stream>>>((const uint4*)g1b, rowptr, adj, dis, b1,
                                            (uint4*)zb, N);
    k_gemm2<<<gblocks, 256, 0, stream>>>(zb, w2f, dis, g2b, N);
    k_agg2<<<(N + 3) / 4, 256, 0, stream>>>((const uint4*)g2b, rowptr, adj, dis, b2, out, N);
}